// Round 13
// baseline (59.423 us; speedup 1.0000x reference)
//
#include <hip/hip_runtime.h>
#include <hip/hip_bf16.h>

typedef __attribute__((ext_vector_type(8))) short bf16x8;
typedef __attribute__((ext_vector_type(4))) float f32x4;

#define NPIX 6272          // 2*56*56
#define HW 56
#define HEADS 8
#define HD 32
#define KW 7
#define DIM 256
#define GDIM 768           // Q|K|V interleaved row stride
#define UK 112             // union keys: 8 rows x 14 cols
#define UKP 128            // padded keys
#define NX (NPIX * DIM)    // 1605632
#define NW (DIM * DIM)     // 65536

__device__ inline short f2bf(float f) {
    __hip_bfloat16 h = __float2bfloat16(f);
    return *(short*)&h;
}
__device__ inline float bf2f(short u) {
    union { unsigned int i; float f; } x;
    x.i = ((unsigned int)(unsigned short)u) << 16;
    return x.f;
}

__device__ __forceinline__ void gl_lds16(const short* g, short* l) {
    __builtin_amdgcn_global_load_lds(
        (const __attribute__((address_space(1))) unsigned int*)g,
        (__attribute__((address_space(3))) unsigned int*)l,
        16, 0, 0);
}

// ---------------- f32 -> bf16 conversion pre-pass ---------------------------
__global__ __launch_bounds__(256) void cvt_kernel(
    const float* __restrict__ X,
    const float* __restrict__ Wq, const float* __restrict__ Wk, const float* __restrict__ Wv,
    short* __restrict__ Xb, short* __restrict__ Wcb)
{
    const size_t e0 = ((size_t)blockIdx.x * 256 + threadIdx.x) * 8;
    const float* src; short* dst; size_t off;
    if (e0 < NX)                { src = X;  dst = Xb;        off = e0; }
    else if (e0 < NX + NW)      { src = Wq; dst = Wcb;       off = e0 - NX; }
    else if (e0 < NX + 2 * NW)  { src = Wk; dst = Wcb + NW;  off = e0 - NX - NW; }
    else                        { src = Wv; dst = Wcb + 2*NW; off = e0 - NX - 2 * NW; }
    float4 f0 = *(const float4*)(src + off);
    float4 f1 = *(const float4*)(src + off + 4);
    bf16x8 v;
    v[0]=f2bf(f0.x); v[1]=f2bf(f0.y); v[2]=f2bf(f0.z); v[3]=f2bf(f0.w);
    v[4]=f2bf(f1.x); v[5]=f2bf(f1.y); v[6]=f2bf(f1.z); v[7]=f2bf(f1.w);
    *(bf16x8*)(dst + off) = v;
}

// ---------------- Projection GEMM: Y[6272][768] = Xb @ Wcat^T + b -----------
// 1-D grid 1176 = 8 XCDs x 147.
__global__ __launch_bounds__(256, 2) void proj_kernel(
    const short* __restrict__ Xb,     // [6272][256] bf16
    const short* __restrict__ Wcb,    // [768][256] bf16
    const float* __restrict__ Bq, const float* __restrict__ Bk, const float* __restrict__ Bv,
    short* __restrict__ Y)            // [6272][768] bf16
{
    __shared__ short Ash[64 * 256];   // 32KB: [row][512B], chunk p holds global chunk p^(row&7)
    __shared__ short Bsh[64 * 256];

    const int id   = blockIdx.x;
    const int flat = (id & 7) * 147 + (id >> 3);
    const int bx   = flat / 12;              // row tile 0..97
    const int by   = flat - bx * 12;         // col tile 0..11

    const int tid  = threadIdx.x;
    const int wave = tid >> 6;
    const int lane = tid & 63;
    const int l15  = lane & 15;
    const int hi   = lane >> 4;

    const int brow = bx * 64;
    const int bcol = by * 64;

    #pragma unroll
    for (int i = 0; i < 8; ++i) {
        const int slot = tid + i * 256;          // 0..2047
        const int row  = slot >> 5;              // 0..63
        const int p    = slot & 31;              // 16B chunk within 512B row
        const int goff = ((p ^ (row & 7)) << 3); // elements (16B = 8 shorts)
        gl_lds16(Xb  + (size_t)(brow + row) * DIM + goff, Ash + slot * 8);
        gl_lds16(Wcb + (size_t)(bcol + row) * DIM + goff, Bsh + slot * 8);
    }
    __syncthreads();

    f32x4 acc[4];
    #pragma unroll
    for (int c = 0; c < 4; ++c) acc[c] = (f32x4){0.f, 0.f, 0.f, 0.f};

    const int arow = wave * 16 + l15;
    #pragma unroll
    for (int kk = 0; kk < 8; ++kk) {
        const int ch = kk * 4 + hi;              // 16B chunk index 0..31
        bf16x8 a = *(const bf16x8*)((char*)Ash + arow * 512 + ((ch ^ (arow & 7)) << 4));
        #pragma unroll
        for (int c = 0; c < 4; ++c) {
            const int bro = c * 16 + l15;
            bf16x8 b = *(const bf16x8*)((char*)Bsh + bro * 512 + ((ch ^ (bro & 7)) << 4));
            acc[c] = __builtin_amdgcn_mfma_f32_16x16x32_bf16(a, b, acc[c], 0, 0, 0);
        }
    }

    const int z = by >> 2;
    const float* Bi = (z == 0) ? Bq : (z == 1) ? Bk : Bv;
    const float scale = (z == 0) ? 0.17677669529663687f : 1.0f;
    #pragma unroll
    for (int c = 0; c < 4; ++c) {
        const int ocol = bcol + c * 16 + l15;
        const float bvv = Bi[ocol & 255];
        #pragma unroll
        for (int r = 0; r < 4; ++r) {
            const int row = brow + wave * 16 + hi * 4 + r;
            Y[(size_t)row * GDIM + ocol] = f2bf((acc[c][r] + bvv) * scale);
        }
    }
}

// ---------------- Neighborhood attention (round-10 version) -----------------
__global__ __launch_bounds__(256, 3) void nattn_kernel(
    const short* __restrict__ Yg,            // [NPIX][768] bf16: Q|K|V
    const float* __restrict__ rpb,           // [8][13][13] f32
    float* __restrict__ out)                 // [NPIX][256] f32
{
    __shared__ short VshT[128 * UKP];            // 32768 B: [d'][key], byte ^= ((d'&7)<<4)
    __shared__ short Psh[4 * 16 * UKP];          // 16384 B: byte ^= (pix<<4)
    __shared__ __align__(16) short rpbs[8 * 169]; // 2704 B bf16

    const int id   = blockIdx.x;
    const int flat = (id & 7) * 98 + (id >> 3);
    const int bz   = flat / 392;
    int rem        = flat - bz * 392;
    const int ip   = rem / 14;
    rem           -= ip * 14;
    const int hg   = rem / 7;
    const int jt   = rem - hg * 7;

    const int tid  = threadIdx.x;
    const int wv   = tid >> 6;
    const int lane = tid & 63;
    const int l15  = lane & 15;
    const int hi   = lane >> 4;

    const int i0 = 2 * ip;
    const int j0 = jt * 8;
    const int r0 = min(max(i0 - 3, 0), HW - KW);
    const int c0 = min(max(j0 - 3, 0), HW - KW);

    const int h = hg * 4 + wv;               // this wave's head

    // ---- batch-issue staging global loads ----------------------------------
    const int k2   = tid & 63;
    const int dblk = tid >> 6;
    const int keyL = 2 * k2, keyR = 2 * k2 + 1;
    const int aL = keyL / 14, cL = keyL - aL * 14;
    const int aR = keyR / 14, cR = keyR - aR * 14;
    const int giL = min(r0 + aL, HW - 1), gjL = min(c0 + cL, HW - 1);
    const int giR = min(r0 + aR, HW - 1), gjR = min(c0 + cR, HW - 1);
    const short* srcL = Yg + (size_t)((bz * HW + giL) * HW + gjL) * GDIM + 512 + hg * 128 + dblk * 32;
    const short* srcR = Yg + (size_t)((bz * HW + giR) * HW + gjR) * GDIM + 512 + hg * 128 + dblk * 32;
    bf16x8 vL[4], vR[4];
    #pragma unroll
    for (int m = 0; m < 4; ++m) {
        vL[m] = (keyL < UK) ? *(const bf16x8*)(srcL + m * 8) : (bf16x8){0,0,0,0,0,0,0,0};
        vR[m] = (keyR < UK) ? *(const bf16x8*)(srcR + m * 8) : (bf16x8){0,0,0,0,0,0,0,0};
    }

    const int qpix = (bz * HW + i0 + (l15 >> 3)) * HW + j0 + (l15 & 7);
    bf16x8 aq = *(const bf16x8*)(Yg + (size_t)qpix * GDIM + h * HD + hi * 8);

    const float4* rpb4 = (const float4*)rpb;
    float4 rv0 = rpb4[tid];
    float4 rv1 = (tid < 338 - 256) ? rpb4[tid + 256] : (float4){0.f,0.f,0.f,0.f};

    // ---- LDS writes --------------------------------------------------------
    #pragma unroll
    for (int m = 0; m < 4; ++m) {
        #pragma unroll
        for (int e = 0; e < 8; ++e) {
            const int d = dblk * 32 + m * 8 + e;          // d&7 == e
            const int w = ((int)(unsigned short)vL[m][e]) | ((int)vR[m][e] << 16);
            *(int*)((char*)VshT + d * 256 + ((4 * k2) ^ (e << 4))) = w;
        }
    }
    *(short4*)(&rpbs[tid * 4]) = make_short4(f2bf(rv0.x), f2bf(rv0.y), f2bf(rv0.z), f2bf(rv0.w));
    if (tid < 338 - 256)
        *(short4*)(&rpbs[(tid + 256) * 4]) = make_short4(f2bf(rv1.x), f2bf(rv1.y), f2bf(rv1.z), f2bf(rv1.w));
    {
        const int p = (lane >> 2) & 15, m4 = lane & 3;
        const int k = UK + m4 * 4;
        char* dst = (char*)Psh + (wv * 16 + p) * 256 + ((2 * k) ^ (p << 4));
        *(int2*)dst = make_int2(0, 0);
    }
    __syncthreads();

    int iv[4], jv[4], bb[4], uai[4], ucj[4];
    #pragma unroll
    for (int r = 0; r < 4; ++r) {
        const int p = hi * 4 + r;
        iv[r] = i0 + (p >> 3);
        jv[r] = j0 + (p & 7);
        const int siv = min(max(iv[r] - 3, 0), HW - KW);
        const int sjv = min(max(jv[r] - 3, 0), HW - KW);
        bb[r]  = (r0 - iv[r] + 6) * 13 + (c0 - jv[r] + 6);
        uai[r] = siv - r0;
        ucj[r] = sjv - c0;
    }
    const f32x4 zf = {0.f, 0.f, 0.f, 0.f};

    // scores: batch-issue 7 K B-frag loads, then 7 MFMAs
    f32x4 sacc[7];
    {
        bf16x8 kb[7];
        #pragma unroll
        for (int t = 0; t < 7; ++t) {
            const int key = t * 16 + l15;
            const int a = key / 14, c = key - a * 14;
            const int gi = min(r0 + a, HW - 1), gj = min(c0 + c, HW - 1);
            kb[t] = *(const bf16x8*)(Yg + (size_t)((bz * HW + gi) * HW + gj) * GDIM +
                                     256 + h * HD + hi * 8);
        }
        #pragma unroll
        for (int t = 0; t < 7; ++t)
            sacc[t] = __builtin_amdgcn_mfma_f32_16x16x32_bf16(aq, kb[t], zf, 0, 0, 0);
    }

    // bias + mask -> sc[r][t]
    const short* rbh = rpbs + h * 169;
    int aA[7], cA[7], a13[7];
    #pragma unroll
    for (int t = 0; t < 7; ++t) {
        const int key = t * 16 + l15;
        aA[t] = key / 14;
        cA[t] = key - aA[t] * 14;
        a13[t] = aA[t] * 13 + cA[t];
    }
    float sc[4][7];
    #pragma unroll
    for (int t = 0; t < 7; ++t) {
        #pragma unroll
        for (int r = 0; r < 4; ++r) {
            const bool ok = ((unsigned)(aA[t] - uai[r]) <= 6u) &
                            ((unsigned)(cA[t] - ucj[r]) <= 6u);
            const float s = sacc[t][r] + bf2f(rbh[bb[r] + a13[t]]);
            sc[r][t] = ok ? s : -1e30f;
        }
    }

    // row max + exp + P store + sum
    float sm[4];
    #pragma unroll
    for (int r = 0; r < 4; ++r) {
        float m = sc[r][0];
        #pragma unroll
        for (int t = 1; t < 7; ++t) m = fmaxf(m, sc[r][t]);
        m = fmaxf(m, __shfl_xor(m, 1));
        m = fmaxf(m, __shfl_xor(m, 2));
        m = fmaxf(m, __shfl_xor(m, 4));
        m = fmaxf(m, __shfl_xor(m, 8));
        const int pix = hi * 4 + r;
        char* prow = (char*)Psh + (wv * 16 + pix) * 256;
        const int pswz = pix << 4;
        float s = 0.f;
        #pragma unroll
        for (int t = 0; t < 7; ++t) {
            const float e = __expf(sc[r][t] - m);
            s += e;
            const int key = t * 16 + l15;
            *(short*)(prow + ((2 * key) ^ pswz)) = f2bf(e);
        }
        s += __shfl_xor(s, 1);
        s += __shfl_xor(s, 2);
        s += __shfl_xor(s, 4);
        s += __shfl_xor(s, 8);
        sm[r] = s;
    }

    // PV: 4 ksteps x 2 dim-tiles
    const int d0 = wv * 32 + l15;
    f32x4 o0 = zf, o1 = zf;
    #pragma unroll
    for (int kk = 0; kk < 4; ++kk) {
        bf16x8 pa = *(const bf16x8*)((char*)Psh + (wv * 16 + l15) * 256 +
                                     ((kk * 64 + hi * 16) ^ (l15 << 4)));
        const int koff = (kk * 64 + hi * 16) ^ ((l15 & 7) << 4);
        bf16x8 vb0 = *(const bf16x8*)((char*)VshT + d0 * 256 + koff);
        bf16x8 vb1 = *(const bf16x8*)((char*)VshT + (d0 + 16) * 256 + koff);
        o0 = __builtin_amdgcn_mfma_f32_16x16x32_bf16(pa, vb0, o0, 0, 0, 0);
        o1 = __builtin_amdgcn_mfma_f32_16x16x32_bf16(pa, vb1, o1, 0, 0, 0);
    }

    // epilogue
    #pragma unroll
    for (int r = 0; r < 4; ++r) {
        const float inv = 1.f / sm[r];
        const int pg = (bz * HW + iv[r]) * HW + jv[r];
        out[(size_t)pg * DIM + h * HD + l15]      = o0[r] * inv;
        out[(size_t)pg * DIM + h * HD + 16 + l15] = o1[r] * inv;
    }
}

extern "C" void kernel_launch(void* const* d_in, const int* in_sizes, int n_in,
                              void* d_out, int out_size, void* d_ws, size_t ws_size,
                              hipStream_t stream) {
    const float* hs = (const float*)d_in[0];
    const float* wq = (const float*)d_in[1];
    const float* bq = (const float*)d_in[2];
    const float* wk = (const float*)d_in[3];
    const float* bk = (const float*)d_in[4];
    const float* wv = (const float*)d_in[5];
    const float* bv = (const float*)d_in[6];
    const float* rpb = (const float*)d_in[7];

    short* Y   = (short*)d_ws;                       // [6272][768]
    short* Xb  = Y + (size_t)NPIX * GDIM;            // [6272][256]
    short* Wcb = Xb + (size_t)NX;                    // [768][256]

    cvt_kernel<<<(NX + 3 * NW) / (256 * 8), 256, 0, stream>>>(hs, wq, wk, wv, Xb, Wcb);

    proj_kernel<<<1176, 256, 0, stream>>>(Xb, Wcb, bq, bk, bv, Y);

    // ABLATION ROUND: nattn launched 3x (idempotent; pure function of Y).
    // Measured delta vs 32.8us = 2 x (nattn + graph-node overhead).
    nattn_kernel<<<784, 256, 0, stream>>>(Y, rpb, (float*)d_out);
    nattn_kernel<<<784, 256, 0, stream>>>(Y, rpb, (float*)d_out);
    nattn_kernel<<<784, 256, 0, stream>>>(Y, rpb, (float*)d_out);
}

// Round 14
// 33.889 us; speedup vs baseline: 1.7535x; 1.7535x over previous
//
#include <hip/hip_runtime.h>
#include <hip/hip_bf16.h>

typedef __attribute__((ext_vector_type(8))) short bf16x8;
typedef __attribute__((ext_vector_type(4))) float f32x4;

#define NPIX 6272          // 2*56*56
#define HW 56
#define HEADS 8
#define HD 32
#define KW 7
#define DIM 256
#define UK 112             // union keys: 8 rows x 14 cols
#define UKP 128            // padded keys
#define NX (NPIX * DIM)    // 1605632
#define NW (DIM * DIM)     // 65536

__device__ inline short f2bf(float f) {
    __hip_bfloat16 h = __float2bfloat16(f);
    return *(short*)&h;
}
__device__ inline float bf2f(short u) {
    union { unsigned int i; float f; } x;
    x.i = ((unsigned int)(unsigned short)u) << 16;
    return x.f;
}

__device__ __forceinline__ void gl_lds16(const short* g, short* l) {
    __builtin_amdgcn_global_load_lds(
        (const __attribute__((address_space(1))) unsigned int*)g,
        (__attribute__((address_space(3))) unsigned int*)l,
        16, 0, 0);
}

// ---------------- f32 -> bf16 conversion pre-pass ---------------------------
__global__ __launch_bounds__(256) void cvt_kernel(
    const float* __restrict__ X,
    const float* __restrict__ Wq, const float* __restrict__ Wk, const float* __restrict__ Wv,
    short* __restrict__ Xb, short* __restrict__ Wcb)
{
    const size_t e0 = ((size_t)blockIdx.x * 256 + threadIdx.x) * 8;
    const float* src; short* dst; size_t off;
    if (e0 < NX)                { src = X;  dst = Xb;        off = e0; }
    else if (e0 < NX + NW)      { src = Wq; dst = Wcb;       off = e0 - NX; }
    else if (e0 < NX + 2 * NW)  { src = Wk; dst = Wcb + NW;  off = e0 - NX - NW; }
    else                        { src = Wv; dst = Wcb + 2*NW; off = e0 - NX - 2 * NW; }
    float4 f0 = *(const float4*)(src + off);
    float4 f1 = *(const float4*)(src + off + 4);
    bf16x8 v;
    v[0]=f2bf(f0.x); v[1]=f2bf(f0.y); v[2]=f2bf(f0.z); v[3]=f2bf(f0.w);
    v[4]=f2bf(f1.x); v[5]=f2bf(f1.y); v[6]=f2bf(f1.z); v[7]=f2bf(f1.w);
    *(bf16x8*)(dst + off) = v;
}

// ---------------- Projection GEMM -> head-major Y ---------------------------
// Y[plane][pix][32], plane = z*8+h (z: 0=q,1=k,2=v). 1-D grid 1176 = 8 x 147.
__global__ __launch_bounds__(256, 2) void proj_kernel(
    const short* __restrict__ Xb,     // [6272][256] bf16
    const short* __restrict__ Wcb,    // [768][256] bf16
    const float* __restrict__ Bq, const float* __restrict__ Bk, const float* __restrict__ Bv,
    short* __restrict__ Y)            // [24][6272][32] bf16
{
    __shared__ short Ash[64 * 256];   // 32KB: [row][512B], chunk p holds global chunk p^(row&7)
    __shared__ short Bsh[64 * 256];

    const int id   = blockIdx.x;
    const int flat = (id & 7) * 147 + (id >> 3);
    const int bx   = flat / 12;              // row tile 0..97
    const int by   = flat - bx * 12;         // col tile 0..11

    const int tid  = threadIdx.x;
    const int wave = tid >> 6;
    const int lane = tid & 63;
    const int l15  = lane & 15;
    const int hi   = lane >> 4;

    const int brow = bx * 64;
    const int bcol = by * 64;

    #pragma unroll
    for (int i = 0; i < 8; ++i) {
        const int slot = tid + i * 256;          // 0..2047
        const int row  = slot >> 5;              // 0..63
        const int p    = slot & 31;              // 16B chunk within 512B row
        const int goff = ((p ^ (row & 7)) << 3); // elements (16B = 8 shorts)
        gl_lds16(Xb  + (size_t)(brow + row) * DIM + goff, Ash + slot * 8);
        gl_lds16(Wcb + (size_t)(bcol + row) * DIM + goff, Bsh + slot * 8);
    }
    __syncthreads();

    f32x4 acc[4];
    #pragma unroll
    for (int c = 0; c < 4; ++c) acc[c] = (f32x4){0.f, 0.f, 0.f, 0.f};

    const int arow = wave * 16 + l15;
    #pragma unroll
    for (int kk = 0; kk < 8; ++kk) {
        const int ch = kk * 4 + hi;              // 16B chunk index 0..31
        bf16x8 a = *(const bf16x8*)((char*)Ash + arow * 512 + ((ch ^ (arow & 7)) << 4));
        #pragma unroll
        for (int c = 0; c < 4; ++c) {
            const int bro = c * 16 + l15;
            bf16x8 b = *(const bf16x8*)((char*)Bsh + bro * 512 + ((ch ^ (bro & 7)) << 4));
            acc[c] = __builtin_amdgcn_mfma_f32_16x16x32_bf16(a, b, acc[c], 0, 0, 0);
        }
    }

    const int z = by >> 2;
    const float* Bi = (z == 0) ? Bq : (z == 1) ? Bk : Bv;
    const float scale = (z == 0) ? 0.17677669529663687f : 1.0f;
    #pragma unroll
    for (int c = 0; c < 4; ++c) {
        const int col256 = (by & 3) * 64 + c * 16 + l15;   // 0..255
        const int h = col256 >> 5;
        const int d = col256 & 31;
        const float bvv = Bi[col256];
        const size_t pbase = (size_t)(z * 8 + h) * NPIX;
        #pragma unroll
        for (int r = 0; r < 4; ++r) {
            const int row = brow + wave * 16 + hi * 4 + r;
            Y[(pbase + row) * 32 + d] = f2bf((acc[c][r] + bvv) * scale);
        }
    }
}

// ---------------- Neighborhood attention, head-major coalesced --------------
// Q plane h, K plane 8+h, V plane 16+h. Same-image-row keys are contiguous
// 64B records -> all gathers are line-dense.
__global__ __launch_bounds__(256, 3) void nattn_kernel(
    const short* __restrict__ Yg,            // [24][6272][32] bf16
    const float* __restrict__ rpb,           // [8][13][13] f32
    float* __restrict__ out)                 // [NPIX][256] f32
{
    __shared__ short VshT[128 * UKP];            // 32768 B: [d'][key], byte ^= ((d'&7)<<4)
    __shared__ short Psh[4 * 16 * UKP];          // 16384 B: byte ^= (pix<<4)
    __shared__ __align__(16) short rpbs[8 * 169]; // 2704 B bf16

    const int id   = blockIdx.x;
    const int flat = (id & 7) * 98 + (id >> 3);
    const int bz   = flat / 392;
    int rem        = flat - bz * 392;
    const int ip   = rem / 14;
    rem           -= ip * 14;
    const int hg   = rem / 7;
    const int jt   = rem - hg * 7;

    const int tid  = threadIdx.x;
    const int wv   = tid >> 6;
    const int lane = tid & 63;
    const int l15  = lane & 15;
    const int hi   = lane >> 4;

    const int i0 = 2 * ip;
    const int j0 = jt * 8;
    const int r0 = min(max(i0 - 3, 0), HW - KW);
    const int c0 = min(max(j0 - 3, 0), HW - KW);

    const int h = hg * 4 + wv;               // this wave's head

    // ---- V staging: coalesced head-major loads -> transposed swizzled LDS --
    // 4 heads x 128 keys x 4 chunks(16B) = 2048 slots = 4x2x256.
    #pragma unroll
    for (int hh = 0; hh < 4; ++hh) {
        const size_t vpl = (size_t)(16 + hg * 4 + hh) * NPIX;
        #pragma unroll
        for (int i = 0; i < 2; ++i) {
            const int slot  = i * 256 + tid;     // 0..511
            const int key   = slot >> 2;         // 0..127
            const int chunk = slot & 3;
            const int a = key / 14, c = key - a * 14;
            const int gi = min(r0 + a, HW - 1), gj = min(c0 + c, HW - 1);
            bf16x8 vv = {0,0,0,0,0,0,0,0};
            if (key < UK)
                vv = *(const bf16x8*)(Yg + (vpl + (bz * HW + gi) * HW + gj) * 32 + chunk * 8);
            #pragma unroll
            for (int e = 0; e < 8; ++e) {
                const int d = chunk * 8 + e;     // d&7 == e
                *(short*)((char*)VshT + (hh * 32 + d) * 256 + ((2 * key) ^ (e << 4))) = vv[e];
            }
        }
    }

    // Q A-frag (head-major: 8 consecutive pixels = 512B contiguous)
    const int qpix = (bz * HW + i0 + (l15 >> 3)) * HW + j0 + (l15 & 7);
    bf16x8 aq = *(const bf16x8*)(Yg + ((size_t)h * NPIX + qpix) * 32 + hi * 8);

    const float4* rpb4 = (const float4*)rpb;
    float4 rv0 = rpb4[tid];
    float4 rv1 = (tid < 338 - 256) ? rpb4[tid + 256] : (float4){0.f,0.f,0.f,0.f};

    *(short4*)(&rpbs[tid * 4]) = make_short4(f2bf(rv0.x), f2bf(rv0.y), f2bf(rv0.z), f2bf(rv0.w));
    if (tid < 338 - 256)
        *(short4*)(&rpbs[(tid + 256) * 4]) = make_short4(f2bf(rv1.x), f2bf(rv1.y), f2bf(rv1.z), f2bf(rv1.w));
    {
        const int p = (lane >> 2) & 15, m4 = lane & 3;
        const int k = UK + m4 * 4;
        char* dst = (char*)Psh + (wv * 16 + p) * 256 + ((2 * k) ^ (p << 4));
        *(int2*)dst = make_int2(0, 0);
    }
    __syncthreads();

    int iv[4], jv[4], bb[4], uai[4], ucj[4];
    #pragma unroll
    for (int r = 0; r < 4; ++r) {
        const int p = hi * 4 + r;
        iv[r] = i0 + (p >> 3);
        jv[r] = j0 + (p & 7);
        const int siv = min(max(iv[r] - 3, 0), HW - KW);
        const int sjv = min(max(jv[r] - 3, 0), HW - KW);
        bb[r]  = (r0 - iv[r] + 6) * 13 + (c0 - jv[r] + 6);
        uai[r] = siv - r0;
        ucj[r] = sjv - c0;
    }
    const f32x4 zf = {0.f, 0.f, 0.f, 0.f};

    // scores: batch-issue 7 K B-frag loads (line-dense), then 7 MFMAs
    f32x4 sacc[7];
    {
        const size_t kpl = (size_t)(8 + h) * NPIX;
        bf16x8 kb[7];
        #pragma unroll
        for (int t = 0; t < 7; ++t) {
            const int key = t * 16 + l15;
            const int a = key / 14, c = key - a * 14;
            const int gi = min(r0 + a, HW - 1), gj = min(c0 + c, HW - 1);
            kb[t] = *(const bf16x8*)(Yg + (kpl + (bz * HW + gi) * HW + gj) * 32 + hi * 8);
        }
        #pragma unroll
        for (int t = 0; t < 7; ++t)
            sacc[t] = __builtin_amdgcn_mfma_f32_16x16x32_bf16(aq, kb[t], zf, 0, 0, 0);
    }

    // bias + mask -> sc[r][t]
    const short* rbh = rpbs + h * 169;
    int aA[7], cA[7], a13[7];
    #pragma unroll
    for (int t = 0; t < 7; ++t) {
        const int key = t * 16 + l15;
        aA[t] = key / 14;
        cA[t] = key - aA[t] * 14;
        a13[t] = aA[t] * 13 + cA[t];
    }
    float sc[4][7];
    #pragma unroll
    for (int t = 0; t < 7; ++t) {
        #pragma unroll
        for (int r = 0; r < 4; ++r) {
            const bool ok = ((unsigned)(aA[t] - uai[r]) <= 6u) &
                            ((unsigned)(cA[t] - ucj[r]) <= 6u);
            const float s = sacc[t][r] + bf2f(rbh[bb[r] + a13[t]]);
            sc[r][t] = ok ? s : -1e30f;
        }
    }

    // row max + exp + P store + sum
    float sm[4];
    #pragma unroll
    for (int r = 0; r < 4; ++r) {
        float m = sc[r][0];
        #pragma unroll
        for (int t = 1; t < 7; ++t) m = fmaxf(m, sc[r][t]);
        m = fmaxf(m, __shfl_xor(m, 1));
        m = fmaxf(m, __shfl_xor(m, 2));
        m = fmaxf(m, __shfl_xor(m, 4));
        m = fmaxf(m, __shfl_xor(m, 8));
        const int pix = hi * 4 + r;
        char* prow = (char*)Psh + (wv * 16 + pix) * 256;
        const int pswz = pix << 4;
        float s = 0.f;
        #pragma unroll
        for (int t = 0; t < 7; ++t) {
            const float e = __expf(sc[r][t] - m);
            s += e;
            const int key = t * 16 + l15;
            *(short*)(prow + ((2 * key) ^ pswz)) = f2bf(e);
        }
        s += __shfl_xor(s, 1);
        s += __shfl_xor(s, 2);
        s += __shfl_xor(s, 4);
        s += __shfl_xor(s, 8);
        sm[r] = s;
    }

    // PV: 4 ksteps x 2 dim-tiles (VshT layout identical to round 10)
    const int d0 = wv * 32 + l15;
    f32x4 o0 = zf, o1 = zf;
    #pragma unroll
    for (int kk = 0; kk < 4; ++kk) {
        bf16x8 pa = *(const bf16x8*)((char*)Psh + (wv * 16 + l15) * 256 +
                                     ((kk * 64 + hi * 16) ^ (l15 << 4)));
        const int koff = (kk * 64 + hi * 16) ^ ((l15 & 7) << 4);
        bf16x8 vb0 = *(const bf16x8*)((char*)VshT + d0 * 256 + koff);
        bf16x8 vb1 = *(const bf16x8*)((char*)VshT + (d0 + 16) * 256 + koff);
        o0 = __builtin_amdgcn_mfma_f32_16x16x32_bf16(pa, vb0, o0, 0, 0, 0);
        o1 = __builtin_amdgcn_mfma_f32_16x16x32_bf16(pa, vb1, o1, 0, 0, 0);
    }

    // epilogue (d_out layout fixed: [pix][256] f32)
    #pragma unroll
    for (int r = 0; r < 4; ++r) {
        const float inv = 1.f / sm[r];
        const int pg = (bz * HW + iv[r]) * HW + jv[r];
        out[(size_t)pg * DIM + h * HD + l15]      = o0[r] * inv;
        out[(size_t)pg * DIM + h * HD + 16 + l15] = o1[r] * inv;
    }
}

extern "C" void kernel_launch(void* const* d_in, const int* in_sizes, int n_in,
                              void* d_out, int out_size, void* d_ws, size_t ws_size,
                              hipStream_t stream) {
    const float* hs = (const float*)d_in[0];
    const float* wq = (const float*)d_in[1];
    const float* bq = (const float*)d_in[2];
    const float* wk = (const float*)d_in[3];
    const float* bk = (const float*)d_in[4];
    const float* wv = (const float*)d_in[5];
    const float* bv = (const float*)d_in[6];
    const float* rpb = (const float*)d_in[7];

    short* Y   = (short*)d_ws;                       // [24][6272][32]
    short* Xb  = Y + (size_t)24 * NPIX * 32;         // [6272][256]
    short* Wcb = Xb + (size_t)NX;                    // [768][256]

    cvt_kernel<<<(NX + 3 * NW) / (256 * 8), 256, 0, stream>>>(hs, wq, wk, wv, Xb, Wcb);

    proj_kernel<<<1176, 256, 0, stream>>>(Xb, Wcb, bq, bk, bv, Y);

    nattn_kernel<<<784, 256, 0, stream>>>(Y, rpb, (float*)d_out);
}

// Round 15
// 33.518 us; speedup vs baseline: 1.7729x; 1.0111x over previous
//
#include <hip/hip_runtime.h>
#include <hip/hip_bf16.h>

typedef __attribute__((ext_vector_type(8))) short bf16x8;
typedef __attribute__((ext_vector_type(4))) float f32x4;

#define NPIX 6272          // 2*56*56
#define HW 56
#define HEADS 8
#define HD 32
#define KW 7
#define DIM 256
#define GDIM 768           // Q|K|V interleaved row stride
#define UK 112             // union keys: 8 rows x 14 cols
#define UKP 128            // padded keys
#define NX (NPIX * DIM)    // 1605632
#define NW (DIM * DIM)     // 65536

__device__ inline short f2bf(float f) {
    __hip_bfloat16 h = __float2bfloat16(f);
    return *(short*)&h;
}
__device__ inline float bf2f(short u) {
    union { unsigned int i; float f; } x;
    x.i = ((unsigned int)(unsigned short)u) << 16;
    return x.f;
}

__device__ __forceinline__ void gl_lds16(const short* g, short* l) {
    __builtin_amdgcn_global_load_lds(
        (const __attribute__((address_space(1))) unsigned int*)g,
        (__attribute__((address_space(3))) unsigned int*)l,
        16, 0, 0);
}

// ---------------- f32 -> bf16 conversion pre-pass ---------------------------
__global__ __launch_bounds__(256) void cvt_kernel(
    const float* __restrict__ X,
    const float* __restrict__ Wq, const float* __restrict__ Wk, const float* __restrict__ Wv,
    short* __restrict__ Xb, short* __restrict__ Wcb)
{
    const size_t e0 = ((size_t)blockIdx.x * 256 + threadIdx.x) * 8;
    const float* src; short* dst; size_t off;
    if (e0 < NX)                { src = X;  dst = Xb;        off = e0; }
    else if (e0 < NX + NW)      { src = Wq; dst = Wcb;       off = e0 - NX; }
    else if (e0 < NX + 2 * NW)  { src = Wk; dst = Wcb + NW;  off = e0 - NX - NW; }
    else                        { src = Wv; dst = Wcb + 2*NW; off = e0 - NX - 2 * NW; }
    float4 f0 = *(const float4*)(src + off);
    float4 f1 = *(const float4*)(src + off + 4);
    bf16x8 v;
    v[0]=f2bf(f0.x); v[1]=f2bf(f0.y); v[2]=f2bf(f0.z); v[3]=f2bf(f0.w);
    v[4]=f2bf(f1.x); v[5]=f2bf(f1.y); v[6]=f2bf(f1.z); v[7]=f2bf(f1.w);
    *(bf16x8*)(dst + off) = v;
}

// ---------------- Projection GEMM: Y[6272][768] = Xb @ Wcat^T + b -----------
// B-tile only in LDS (32 KB -> up to 5 blocks/CU, single dispatch round).
// A-fragments global->VGPR, batch-issued before the staging barrier.
// 1-D grid 1176 = 8 XCDs x 147.
__global__ __launch_bounds__(256, 4) void proj_kernel(
    const short* __restrict__ Xb,     // [6272][256] bf16
    const short* __restrict__ Wcb,    // [768][256] bf16
    const float* __restrict__ Bq, const float* __restrict__ Bk, const float* __restrict__ Bv,
    short* __restrict__ Y)            // [6272][768] bf16
{
    __shared__ short Bsh[64 * 256];   // 32KB: [row][512B], chunk p holds global chunk p^(row&7)

    const int id   = blockIdx.x;
    const int flat = (id & 7) * 147 + (id >> 3);
    const int bx   = flat / 12;              // row tile 0..97
    const int by   = flat - bx * 12;         // col tile 0..11

    const int tid  = threadIdx.x;
    const int wave = tid >> 6;
    const int lane = tid & 63;
    const int l15  = lane & 15;
    const int hi   = lane >> 4;

    const int brow = bx * 64;
    const int bcol = by * 64;

    // ---- batch-issue A-fragment loads (8 x bf16x8 per lane) ----
    const short* xrow = Xb + (size_t)(brow + wave * 16 + l15) * DIM;
    bf16x8 a8[8];
    #pragma unroll
    for (int kk = 0; kk < 8; ++kk) a8[kk] = *(const bf16x8*)(xrow + kk * 32 + hi * 8);

    // ---- stage B tile via global_load_lds (coalesced, inverse-swizzled) ----
    #pragma unroll
    for (int i = 0; i < 8; ++i) {
        const int slot = tid + i * 256;          // 0..2047
        const int row  = slot >> 5;              // 0..63
        const int p    = slot & 31;              // 16B chunk within 512B row
        const int goff = ((p ^ (row & 7)) << 3); // elements (16B = 8 shorts)
        gl_lds16(Wcb + (size_t)(bcol + row) * DIM + goff, Bsh + slot * 8);
    }
    __syncthreads();

    f32x4 acc[4];
    #pragma unroll
    for (int c = 0; c < 4; ++c) acc[c] = (f32x4){0.f, 0.f, 0.f, 0.f};

    #pragma unroll
    for (int kk = 0; kk < 8; ++kk) {
        const int ch = kk * 4 + hi;              // 16B chunk index 0..31
        #pragma unroll
        for (int c = 0; c < 4; ++c) {
            const int bro = c * 16 + l15;
            bf16x8 b = *(const bf16x8*)((char*)Bsh + bro * 512 + ((ch ^ (bro & 7)) << 4));
            acc[c] = __builtin_amdgcn_mfma_f32_16x16x32_bf16(a8[kk], b, acc[c], 0, 0, 0);
        }
    }

    const int z = by >> 2;
    const float* Bi = (z == 0) ? Bq : (z == 1) ? Bk : Bv;
    const float scale = (z == 0) ? 0.17677669529663687f : 1.0f;
    #pragma unroll
    for (int c = 0; c < 4; ++c) {
        const int ocol = bcol + c * 16 + l15;
        const float bvv = Bi[ocol & 255];
        #pragma unroll
        for (int r = 0; r < 4; ++r) {
            const int row = brow + wave * 16 + hi * 4 + r;
            Y[(size_t)row * GDIM + ocol] = f2bf((acc[c][r] + bvv) * scale);
        }
    }
}

// ---------------- Neighborhood attention (byte-identical to round 10) -------
__global__ __launch_bounds__(256, 3) void nattn_kernel(
    const short* __restrict__ Yg,            // [NPIX][768] bf16: Q|K|V
    const float* __restrict__ rpb,           // [8][13][13] f32
    float* __restrict__ out)                 // [NPIX][256] f32
{
    __shared__ short VshT[128 * UKP];            // 32768 B: [d'][key], byte ^= ((d'&7)<<4)
    __shared__ short Psh[4 * 16 * UKP];          // 16384 B: byte ^= (pix<<4)
    __shared__ __align__(16) short rpbs[8 * 169]; // 2704 B bf16

    const int id   = blockIdx.x;
    const int flat = (id & 7) * 98 + (id >> 3);
    const int bz   = flat / 392;
    int rem        = flat - bz * 392;
    const int ip   = rem / 14;
    rem           -= ip * 14;
    const int hg   = rem / 7;
    const int jt   = rem - hg * 7;

    const int tid  = threadIdx.x;
    const int wv   = tid >> 6;
    const int lane = tid & 63;
    const int l15  = lane & 15;
    const int hi   = lane >> 4;

    const int i0 = 2 * ip;
    const int j0 = jt * 8;
    const int r0 = min(max(i0 - 3, 0), HW - KW);
    const int c0 = min(max(j0 - 3, 0), HW - KW);

    const int h = hg * 4 + wv;               // this wave's head

    // ---- batch-issue staging global loads ----------------------------------
    const int k2   = tid & 63;
    const int dblk = tid >> 6;
    const int keyL = 2 * k2, keyR = 2 * k2 + 1;
    const int aL = keyL / 14, cL = keyL - aL * 14;
    const int aR = keyR / 14, cR = keyR - aR * 14;
    const int giL = min(r0 + aL, HW - 1), gjL = min(c0 + cL, HW - 1);
    const int giR = min(r0 + aR, HW - 1), gjR = min(c0 + cR, HW - 1);
    const short* srcL = Yg + (size_t)((bz * HW + giL) * HW + gjL) * GDIM + 512 + hg * 128 + dblk * 32;
    const short* srcR = Yg + (size_t)((bz * HW + giR) * HW + gjR) * GDIM + 512 + hg * 128 + dblk * 32;
    bf16x8 vL[4], vR[4];
    #pragma unroll
    for (int m = 0; m < 4; ++m) {
        vL[m] = (keyL < UK) ? *(const bf16x8*)(srcL + m * 8) : (bf16x8){0,0,0,0,0,0,0,0};
        vR[m] = (keyR < UK) ? *(const bf16x8*)(srcR + m * 8) : (bf16x8){0,0,0,0,0,0,0,0};
    }

    const int qpix = (bz * HW + i0 + (l15 >> 3)) * HW + j0 + (l15 & 7);
    bf16x8 aq = *(const bf16x8*)(Yg + (size_t)qpix * GDIM + h * HD + hi * 8);

    const float4* rpb4 = (const float4*)rpb;
    float4 rv0 = rpb4[tid];
    float4 rv1 = (tid < 338 - 256) ? rpb4[tid + 256] : (float4){0.f,0.f,0.f,0.f};

    // ---- LDS writes --------------------------------------------------------
    #pragma unroll
    for (int m = 0; m < 4; ++m) {
        #pragma unroll
        for (int e = 0; e < 8; ++e) {
            const int d = dblk * 32 + m * 8 + e;          // d&7 == e
            const int w = ((int)(unsigned short)vL[m][e]) | ((int)vR[m][e] << 16);
            *(int*)((char*)VshT + d * 256 + ((4 * k2) ^ (e << 4))) = w;
        }
    }
    *(short4*)(&rpbs[tid * 4]) = make_short4(f2bf(rv0.x), f2bf(rv0.y), f2bf(rv0.z), f2bf(rv0.w));
    if (tid < 338 - 256)
        *(short4*)(&rpbs[(tid + 256) * 4]) = make_short4(f2bf(rv1.x), f2bf(rv1.y), f2bf(rv1.z), f2bf(rv1.w));
    {
        const int p = (lane >> 2) & 15, m4 = lane & 3;
        const int k = UK + m4 * 4;
        char* dst = (char*)Psh + (wv * 16 + p) * 256 + ((2 * k) ^ (p << 4));
        *(int2*)dst = make_int2(0, 0);
    }
    __syncthreads();

    int iv[4], jv[4], bb[4], uai[4], ucj[4];
    #pragma unroll
    for (int r = 0; r < 4; ++r) {
        const int p = hi * 4 + r;
        iv[r] = i0 + (p >> 3);
        jv[r] = j0 + (p & 7);
        const int siv = min(max(iv[r] - 3, 0), HW - KW);
        const int sjv = min(max(jv[r] - 3, 0), HW - KW);
        bb[r]  = (r0 - iv[r] + 6) * 13 + (c0 - jv[r] + 6);
        uai[r] = siv - r0;
        ucj[r] = sjv - c0;
    }
    const f32x4 zf = {0.f, 0.f, 0.f, 0.f};

    // scores: batch-issue 7 K B-frag loads, then 7 MFMAs
    f32x4 sacc[7];
    {
        bf16x8 kb[7];
        #pragma unroll
        for (int t = 0; t < 7; ++t) {
            const int key = t * 16 + l15;
            const int a = key / 14, c = key - a * 14;
            const int gi = min(r0 + a, HW - 1), gj = min(c0 + c, HW - 1);
            kb[t] = *(const bf16x8*)(Yg + (size_t)((bz * HW + gi) * HW + gj) * GDIM +
                                     256 + h * HD + hi * 8);
        }
        #pragma unroll
        for (int t = 0; t < 7; ++t)
            sacc[t] = __builtin_amdgcn_mfma_f32_16x16x32_bf16(aq, kb[t], zf, 0, 0, 0);
    }

    // bias + mask -> sc[r][t]
    const short* rbh = rpbs + h * 169;
    int aA[7], cA[7], a13[7];
    #pragma unroll
    for (int t = 0; t < 7; ++t) {
        const int key = t * 16 + l15;
        aA[t] = key / 14;
        cA[t] = key - aA[t] * 14;
        a13[t] = aA[t] * 13 + cA[t];
    }
    float sc[4][7];
    #pragma unroll
    for (int t = 0; t < 7; ++t) {
        #pragma unroll
        for (int r = 0; r < 4; ++r) {
            const bool ok = ((unsigned)(aA[t] - uai[r]) <= 6u) &
                            ((unsigned)(cA[t] - ucj[r]) <= 6u);
            const float s = sacc[t][r] + bf2f(rbh[bb[r] + a13[t]]);
            sc[r][t] = ok ? s : -1e30f;
        }
    }

    // row max + exp + P store + sum
    float sm[4];
    #pragma unroll
    for (int r = 0; r < 4; ++r) {
        float m = sc[r][0];
        #pragma unroll
        for (int t = 1; t < 7; ++t) m = fmaxf(m, sc[r][t]);
        m = fmaxf(m, __shfl_xor(m, 1));
        m = fmaxf(m, __shfl_xor(m, 2));
        m = fmaxf(m, __shfl_xor(m, 4));
        m = fmaxf(m, __shfl_xor(m, 8));
        const int pix = hi * 4 + r;
        char* prow = (char*)Psh + (wv * 16 + pix) * 256;
        const int pswz = pix << 4;
        float s = 0.f;
        #pragma unroll
        for (int t = 0; t < 7; ++t) {
            const float e = __expf(sc[r][t] - m);
            s += e;
            const int key = t * 16 + l15;
            *(short*)(prow + ((2 * key) ^ pswz)) = f2bf(e);
        }
        s += __shfl_xor(s, 1);
        s += __shfl_xor(s, 2);
        s += __shfl_xor(s, 4);
        s += __shfl_xor(s, 8);
        sm[r] = s;
    }

    // PV: 4 ksteps x 2 dim-tiles
    const int d0 = wv * 32 + l15;
    f32x4 o0 = zf, o1 = zf;
    #pragma unroll
    for (int kk = 0; kk < 4; ++kk) {
        bf16x8 pa = *(const bf16x8*)((char*)Psh + (wv * 16 + l15) * 256 +
                                     ((kk * 64 + hi * 16) ^ (l15 << 4)));
        const int koff = (kk * 64 + hi * 16) ^ ((l15 & 7) << 4);
        bf16x8 vb0 = *(const bf16x8*)((char*)VshT + d0 * 256 + koff);
        bf16x8 vb1 = *(const bf16x8*)((char*)VshT + (d0 + 16) * 256 + koff);
        o0 = __builtin_amdgcn_mfma_f32_16x16x32_bf16(pa, vb0, o0, 0, 0, 0);
        o1 = __builtin_amdgcn_mfma_f32_16x16x32_bf16(pa, vb1, o1, 0, 0, 0);
    }

    // epilogue
    #pragma unroll
    for (int r = 0; r < 4; ++r) {
        const float inv = 1.f / sm[r];
        const int pg = (bz * HW + iv[r]) * HW + jv[r];
        out[(size_t)pg * DIM + h * HD + l15]      = o0[r] * inv;
        out[(size_t)pg * DIM + h * HD + 16 + l15] = o1[r] * inv;
    }
}

extern "C" void kernel_launch(void* const* d_in, const int* in_sizes, int n_in,
                              void* d_out, int out_size, void* d_ws, size_t ws_size,
                              hipStream_t stream) {
    const float* hs = (const float*)d_in[0];
    const float* wq = (const float*)d_in[1];
    const float* bq = (const float*)d_in[2];
    const float* wk = (const float*)d_in[3];
    const float* bk = (const float*)d_in[4];
    const float* wv = (const float*)d_in[5];
    const float* bv = (const float*)d_in[6];
    const float* rpb = (const float*)d_in[7];

    short* Y   = (short*)d_ws;                       // [6272][768]
    short* Xb  = Y + (size_t)NPIX * GDIM;            // [6272][256]
    short* Wcb = Xb + (size_t)NX;                    // [768][256]

    cvt_kernel<<<(NX + 3 * NW) / (256 * 8), 256, 0, stream>>>(hs, wq, wk, wv, Xb, Wcb);

    proj_kernel<<<1176, 256, 0, stream>>>(Xb, Wcb, bq, bk, bv, Y);

    nattn_kernel<<<784, 256, 0, stream>>>(Y, rpb, (float*)d_out);
}

// Round 16
// 31.251 us; speedup vs baseline: 1.9015x; 1.0725x over previous
//
#include <hip/hip_runtime.h>
#include <hip/hip_bf16.h>

typedef __attribute__((ext_vector_type(8))) short bf16x8;
typedef __attribute__((ext_vector_type(4))) float f32x4;

#define NPIX 6272          // 2*56*56
#define HW 56
#define HEADS 8
#define HD 32
#define KW 7
#define DIM 256
#define GDIM 768           // Q|K|V interleaved row stride
#define UK 112             // union keys: 8 rows x 14 cols
#define UKP 128            // padded keys
#define NX (NPIX * DIM)    // 1605632
#define NW (DIM * DIM)     // 65536

__device__ inline short f2bf(float f) {
    __hip_bfloat16 h = __float2bfloat16(f);
    return *(short*)&h;
}
__device__ inline float bf2f(short u) {
    union { unsigned int i; float f; } x;
    x.i = ((unsigned int)(unsigned short)u) << 16;
    return x.f;
}

__device__ __forceinline__ void gl_lds16(const short* g, short* l) {
    __builtin_amdgcn_global_load_lds(
        (const __attribute__((address_space(1))) unsigned int*)g,
        (__attribute__((address_space(3))) unsigned int*)l,
        16, 0, 0);
}

// ---------------- f32 -> bf16 conversion pre-pass ---------------------------
__global__ __launch_bounds__(256) void cvt_kernel(
    const float* __restrict__ X,
    const float* __restrict__ Wq, const float* __restrict__ Wk, const float* __restrict__ Wv,
    short* __restrict__ Xb, short* __restrict__ Wcb)
{
    const size_t e0 = ((size_t)blockIdx.x * 256 + threadIdx.x) * 8;
    const float* src; short* dst; size_t off;
    if (e0 < NX)                { src = X;  dst = Xb;        off = e0; }
    else if (e0 < NX + NW)      { src = Wq; dst = Wcb;       off = e0 - NX; }
    else if (e0 < NX + 2 * NW)  { src = Wk; dst = Wcb + NW;  off = e0 - NX - NW; }
    else                        { src = Wv; dst = Wcb + 2*NW; off = e0 - NX - 2 * NW; }
    float4 f0 = *(const float4*)(src + off);
    float4 f1 = *(const float4*)(src + off + 4);
    bf16x8 v;
    v[0]=f2bf(f0.x); v[1]=f2bf(f0.y); v[2]=f2bf(f0.z); v[3]=f2bf(f0.w);
    v[4]=f2bf(f1.x); v[5]=f2bf(f1.y); v[6]=f2bf(f1.z); v[7]=f2bf(f1.w);
    *(bf16x8*)(dst + off) = v;
}

// ---------------- Projection GEMM (round-10 exact form) ---------------------
__global__ __launch_bounds__(256, 2) void proj_kernel(
    const short* __restrict__ Xb,     // [6272][256] bf16
    const short* __restrict__ Wcb,    // [768][256] bf16
    const float* __restrict__ Bq, const float* __restrict__ Bk, const float* __restrict__ Bv,
    short* __restrict__ Y)            // [6272][768] bf16
{
    __shared__ short Ash[64 * 256];   // 32KB: [row][512B], chunk p holds global chunk p^(row&7)
    __shared__ short Bsh[64 * 256];

    const int id   = blockIdx.x;
    const int flat = (id & 7) * 147 + (id >> 3);
    const int bx   = flat / 12;              // row tile 0..97
    const int by   = flat - bx * 12;         // col tile 0..11

    const int tid  = threadIdx.x;
    const int wave = tid >> 6;
    const int lane = tid & 63;
    const int l15  = lane & 15;
    const int hi   = lane >> 4;

    const int brow = bx * 64;
    const int bcol = by * 64;

    #pragma unroll
    for (int i = 0; i < 8; ++i) {
        const int slot = tid + i * 256;          // 0..2047
        const int row  = slot >> 5;              // 0..63
        const int p    = slot & 31;              // 16B chunk within 512B row
        const int goff = ((p ^ (row & 7)) << 3); // elements (16B = 8 shorts)
        gl_lds16(Xb  + (size_t)(brow + row) * DIM + goff, Ash + slot * 8);
        gl_lds16(Wcb + (size_t)(bcol + row) * DIM + goff, Bsh + slot * 8);
    }
    __syncthreads();

    f32x4 acc[4];
    #pragma unroll
    for (int c = 0; c < 4; ++c) acc[c] = (f32x4){0.f, 0.f, 0.f, 0.f};

    const int arow = wave * 16 + l15;
    #pragma unroll
    for (int kk = 0; kk < 8; ++kk) {
        const int ch = kk * 4 + hi;              // 16B chunk index 0..31
        bf16x8 a = *(const bf16x8*)((char*)Ash + arow * 512 + ((ch ^ (arow & 7)) << 4));
        #pragma unroll
        for (int c = 0; c < 4; ++c) {
            const int bro = c * 16 + l15;
            bf16x8 b = *(const bf16x8*)((char*)Bsh + bro * 512 + ((ch ^ (bro & 7)) << 4));
            acc[c] = __builtin_amdgcn_mfma_f32_16x16x32_bf16(a, b, acc[c], 0, 0, 0);
        }
    }

    const int z = by >> 2;
    const float* Bi = (z == 0) ? Bq : (z == 1) ? Bk : Bv;
    const float scale = (z == 0) ? 0.17677669529663687f : 1.0f;
    #pragma unroll
    for (int c = 0; c < 4; ++c) {
        const int ocol = bcol + c * 16 + l15;
        const float bvv = Bi[ocol & 255];
        #pragma unroll
        for (int r = 0; r < 4; ++r) {
            const int row = brow + wave * 16 + hi * 4 + r;
            Y[(size_t)row * GDIM + ocol] = f2bf((acc[c][r] + bvv) * scale);
        }
    }
}

// ---------------- Neighborhood attention, swapped-QK^T, no Psh --------------
// LDS = VshT 32K + rpbs 2.7K = 34.7K -> 4 blocks/CU -> 784 blocks in ONE
// dispatch round. mfma(K,Q) puts S^T in regs: lane(l15,hi) owns pixel l15,
// keys {16t+4hi+r}. P stays in registers; PV B-frag built via 64-bit shuffles.
__global__ __launch_bounds__(256, 4) void nattn_kernel(
    const short* __restrict__ Yg,            // [NPIX][768] bf16: Q|K|V
    const float* __restrict__ rpb,           // [8][13][13] f32
    float* __restrict__ out)                 // [NPIX][256] f32
{
    __shared__ short VshT[128 * UKP];            // 32768 B: [d'][key], byte ^= ((d'&7)<<4)
    __shared__ __align__(16) short rpbs[8 * 169]; // 2704 B bf16

    const int id   = blockIdx.x;
    const int flat = (id & 7) * 98 + (id >> 3);
    const int bz   = flat / 392;
    int rem        = flat - bz * 392;
    const int ip   = rem / 14;
    rem           -= ip * 14;
    const int hg   = rem / 7;
    const int jt   = rem - hg * 7;

    const int tid  = threadIdx.x;
    const int wv   = tid >> 6;
    const int lane = tid & 63;
    const int l15  = lane & 15;
    const int hi   = lane >> 4;

    const int i0 = 2 * ip;
    const int j0 = jt * 8;
    const int r0 = min(max(i0 - 3, 0), HW - KW);
    const int c0 = min(max(j0 - 3, 0), HW - KW);

    const int h = hg * 4 + wv;               // this wave's head

    // ---- batch-issue V staging loads ---------------------------------------
    const int k2   = tid & 63;
    const int dblk = tid >> 6;
    const int keyL = 2 * k2, keyR = 2 * k2 + 1;
    const int aL = keyL / 14, cL = keyL - aL * 14;
    const int aR = keyR / 14, cR = keyR - aR * 14;
    const int giL = min(r0 + aL, HW - 1), gjL = min(c0 + cL, HW - 1);
    const int giR = min(r0 + aR, HW - 1), gjR = min(c0 + cR, HW - 1);
    const short* srcL = Yg + (size_t)((bz * HW + giL) * HW + gjL) * GDIM + 512 + hg * 128 + dblk * 32;
    const short* srcR = Yg + (size_t)((bz * HW + giR) * HW + gjR) * GDIM + 512 + hg * 128 + dblk * 32;
    bf16x8 vL[4], vR[4];
    #pragma unroll
    for (int m = 0; m < 4; ++m) {
        vL[m] = (keyL < UK) ? *(const bf16x8*)(srcL + m * 8) : (bf16x8){0,0,0,0,0,0,0,0};
        vR[m] = (keyR < UK) ? *(const bf16x8*)(srcR + m * 8) : (bf16x8){0,0,0,0,0,0,0,0};
    }

    const int qpix = (bz * HW + i0 + (l15 >> 3)) * HW + j0 + (l15 & 7);
    bf16x8 aq = *(const bf16x8*)(Yg + (size_t)qpix * GDIM + h * HD + hi * 8);

    const float4* rpb4 = (const float4*)rpb;
    float4 rv0 = rpb4[tid];
    float4 rv1 = (tid < 338 - 256) ? rpb4[tid + 256] : (float4){0.f,0.f,0.f,0.f};

    // ---- LDS writes --------------------------------------------------------
    #pragma unroll
    for (int m = 0; m < 4; ++m) {
        #pragma unroll
        for (int e = 0; e < 8; ++e) {
            const int d = dblk * 32 + m * 8 + e;          // d&7 == e
            const int w = ((int)(unsigned short)vL[m][e]) | ((int)vR[m][e] << 16);
            *(int*)((char*)VshT + d * 256 + ((4 * k2) ^ (e << 4))) = w;
        }
    }
    *(short4*)(&rpbs[tid * 4]) = make_short4(f2bf(rv0.x), f2bf(rv0.y), f2bf(rv0.z), f2bf(rv0.w));
    if (tid < 338 - 256)
        *(short4*)(&rpbs[(tid + 256) * 4]) = make_short4(f2bf(rv1.x), f2bf(rv1.y), f2bf(rv1.z), f2bf(rv1.w));
    __syncthreads();

    // ---- per-lane pixel (l15) metadata -------------------------------------
    const int iv = i0 + (l15 >> 3);
    const int jv = j0 + (l15 & 7);
    const int siv = min(max(iv - 3, 0), HW - KW);
    const int sjv = min(max(jv - 3, 0), HW - KW);
    const int bb  = (r0 - iv + 6) * 13 + (c0 - jv + 6);
    const int uai = siv - r0;
    const int ucj = sjv - c0;
    const f32x4 zf = {0.f, 0.f, 0.f, 0.f};

    // ---- scores (swapped): sacc[t] = K_tile^T x Q -> S^T -------------------
    // lane(l15,hi) gets S[key=16t+4hi+r][pix=l15]
    f32x4 sacc[7];
    {
        bf16x8 kb[7];
        #pragma unroll
        for (int t = 0; t < 7; ++t) {
            const int key = t * 16 + l15;
            const int a = key / 14, c = key - a * 14;
            const int gi = min(r0 + a, HW - 1), gj = min(c0 + c, HW - 1);
            kb[t] = *(const bf16x8*)(Yg + (size_t)((bz * HW + gi) * HW + gj) * GDIM +
                                     256 + h * HD + hi * 8);
        }
        #pragma unroll
        for (int t = 0; t < 7; ++t)
            sacc[t] = __builtin_amdgcn_mfma_f32_16x16x32_bf16(kb[t], aq, zf, 0, 0, 0);
    }

    // ---- bias + mask (pixel fixed = l15; 28 keys in-register) --------------
    const short* rbh = rpbs + h * 169;
    float sc[7][4];
    #pragma unroll
    for (int t = 0; t < 7; ++t) {
        #pragma unroll
        for (int r = 0; r < 4; ++r) {
            const int key = t * 16 + (hi << 2) + r;
            const int a = key / 14, c = key - a * 14;
            const bool ok = ((unsigned)(a - uai) <= 6u) & ((unsigned)(c - ucj) <= 6u);
            const float s = sacc[t][r] + bf2f(rbh[bb + a * 13 + c]);
            sc[t][r] = ok ? s : -1e30f;
        }
    }

    // ---- softmax over keys for pixel l15 (28 regs + 2 shfls) ---------------
    float m = sc[0][0];
    #pragma unroll
    for (int t = 0; t < 7; ++t)
        #pragma unroll
        for (int r = 0; r < 4; ++r) m = fmaxf(m, sc[t][r]);
    m = fmaxf(m, __shfl_xor(m, 16));
    m = fmaxf(m, __shfl_xor(m, 32));

    float sm = 0.f;
    unsigned long long pk[7];
    #pragma unroll
    for (int t = 0; t < 7; ++t) {
        float e0 = __expf(sc[t][0] - m), e1 = __expf(sc[t][1] - m);
        float e2 = __expf(sc[t][2] - m), e3 = __expf(sc[t][3] - m);
        sm += (e0 + e1) + (e2 + e3);
        const unsigned u0 = (unsigned)(unsigned short)f2bf(e0) |
                            ((unsigned)(unsigned short)f2bf(e1) << 16);
        const unsigned u1 = (unsigned)(unsigned short)f2bf(e2) |
                            ((unsigned)(unsigned short)f2bf(e3) << 16);
        pk[t] = (unsigned long long)u0 | ((unsigned long long)u1 << 32);
    }
    sm += __shfl_xor(sm, 16);
    sm += __shfl_xor(sm, 32);

    // ---- PV: O^T = V^T x P^T; P^T B-frags via 64-bit shuffles --------------
    const int s0 = l15 + ((hi & 1) << 5);    // src lane for low half (h_src=2*(hi&1))
    const bool hiSel = (hi >> 1) & 1;
    const int d0 = wv * 32 + l15;            // VshT row for dt=0 (d0&7 == l15&7)
    f32x4 o0 = zf, o1 = zf;
    #pragma unroll
    for (int kk = 0; kk < 4; ++kk) {
        unsigned long long a0 = __shfl(pk[2 * kk], s0, 64);
        unsigned long long b0 = __shfl(pk[2 * kk], s0 + 16, 64);
        unsigned long long a1 = 0ULL, b1 = 0ULL;
        if (2 * kk + 1 < 7) {
            a1 = __shfl(pk[2 * kk + 1], s0, 64);
            b1 = __shfl(pk[2 * kk + 1], s0 + 16, 64);
        }
        bf16x8 pa;
        ((unsigned long long*)&pa)[0] = hiSel ? a1 : a0;
        ((unsigned long long*)&pa)[1] = hiSel ? b1 : b0;

        const int koff = (kk * 64 + hi * 16) ^ ((l15 & 7) << 4);
        bf16x8 va0 = *(const bf16x8*)((char*)VshT + d0 * 256 + koff);
        bf16x8 va1 = *(const bf16x8*)((char*)VshT + (d0 + 16) * 256 + koff);
        o0 = __builtin_amdgcn_mfma_f32_16x16x32_bf16(va0, pa, o0, 0, 0, 0);
        o1 = __builtin_amdgcn_mfma_f32_16x16x32_bf16(va1, pa, o1, 0, 0, 0);
    }

    // ---- epilogue: lane(l15,hi) holds O[pix=l15][d = dt*16 + hi*4 + r] -----
    const float inv = 1.f / sm;
    float4 w0, w1;
    w0.x = o0[0] * inv; w0.y = o0[1] * inv; w0.z = o0[2] * inv; w0.w = o0[3] * inv;
    w1.x = o1[0] * inv; w1.y = o1[1] * inv; w1.z = o1[2] * inv; w1.w = o1[3] * inv;
    float* orow = out + (size_t)qpix * DIM + h * HD + hi * 4;
    *(float4*)(orow)      = w0;
    *(float4*)(orow + 16) = w1;
}

extern "C" void kernel_launch(void* const* d_in, const int* in_sizes, int n_in,
                              void* d_out, int out_size, void* d_ws, size_t ws_size,
                              hipStream_t stream) {
    const float* hs = (const float*)d_in[0];
    const float* wq = (const float*)d_in[1];
    const float* bq = (const float*)d_in[2];
    const float* wk = (const float*)d_in[3];
    const float* bk = (const float*)d_in[4];
    const float* wv = (const float*)d_in[5];
    const float* bv = (const float*)d_in[6];
    const float* rpb = (const float*)d_in[7];

    short* Y   = (short*)d_ws;                       // [6272][768]
    short* Xb  = Y + (size_t)NPIX * GDIM;            // [6272][256]
    short* Wcb = Xb + (size_t)NX;                    // [768][256]

    cvt_kernel<<<(NX + 3 * NW) / (256 * 8), 256, 0, stream>>>(hs, wq, wk, wv, Xb, Wcb);

    proj_kernel<<<1176, 256, 0, stream>>>(Xb, Wcb, bq, bk, bv, Y);

    nattn_kernel<<<784, 256, 0, stream>>>(Y, rpb, (float*)d_out);
}